// Round 6
// baseline (91.578 us; speedup 1.0000x reference)
//
#include <hip/hip_runtime.h>

// x:(32,1,512,512) f32, theta:(4,) f32
// out flat layout (reference raw .view): out_flat[l*128 + b*4 + q],
//   l = i*256 + j (patch index), b = batch, q = qubit  -> float4 units: out4[l*32+b]
#define BATCH 32
#define HH 512
#define WW 512
#define HO 256
#define WO 256
#define LTOT (HO * WO) // 65536 patches per image

// sin/cos of a/2 via hardware v_sin/v_cos (input in revolutions: a/2 / 2pi = a/(4pi)).
// |a| <~ 6 for N(0,1) inputs -> |r| <= 0.5, no range reduction needed; ~4 ULP accuracy.
#define INV_4PI 0.07957747154594767f

__global__ __launch_bounds__(256) void quanv_kernel(const float* __restrict__ x,
                                                    const float* __restrict__ theta,
                                                    float* __restrict__ out) {
    // 32 KB staging: slot = lsub*32 + (b ^ (lsub&31)); 2-way (free) on writes,
    // permutation (conflict-free) on the linear read-out.
    __shared__ float4 lds[2048];

    const int tid   = threadIdx.x;
    const int l0    = blockIdx.x * 64;   // 64 consecutive patches (same image row)
    const int irow  = l0 >> 8;
    const int j0    = l0 & 255;
    const int lpair = tid & 31;          // patch-pair 0..31 -> patches 2*lpair, 2*lpair+1
    const int b0    = tid >> 5;          // 0..7

    // Trainable-layer rotations (uniform): c/s of theta/2 via hardware sin/cos
    float ct[4], st[4];
#pragma unroll
    for (int q = 0; q < 4; ++q) {
        const float r = theta[q] * INV_4PI;
        st[q] = __builtin_amdgcn_sinf(r);
        ct[q] = __builtin_amdgcn_cosf(r);
    }

    const int col  = 2 * (j0 + 2 * lpair);      // leftmost pixel column of the pair
    const int off0 = (2 * irow) * WW + col;     // row 2i
    const int off1 = off0 + WW;                 // row 2i+1

#pragma unroll
    for (int pp = 0; pp < 4; ++pp) {
        const int b = b0 + pp * 8;
        const float* xb = x + (size_t)b * (HH * WW);
        const float4 r0 = *(const float4*)(xb + off0);  // 2 patches x 2 pixels, row 2i
        const float4 r1 = *(const float4*)(xb + off1);  // 2 patches x 2 pixels, row 2i+1

#pragma unroll
        for (int c = 0; c < 2; ++c) {
            const float aa[4] = {c ? r0.z : r0.x, c ? r0.w : r0.y,
                                 c ? r1.z : r1.x, c ? r1.w : r1.y};
            float pc[4], ps[4];
#pragma unroll
            for (int k = 0; k < 4; ++k) {
                const float r = aa[k] * INV_4PI;
                ps[k] = __builtin_amdgcn_sinf(r);
                pc[k] = __builtin_amdgcn_cosf(r);
            }

            // Product state; state index s: qubit q <-> bit (8>>q)
            float amp[16];
#pragma unroll
            for (int s = 0; s < 16; ++s) {
                float v = ((s & 8) ? ps[0] : pc[0]);
                v *= ((s & 4) ? ps[1] : pc[1]);
                v *= ((s & 2) ? ps[2] : pc[2]);
                v *= ((s & 1) ? ps[3] : pc[3]);
                amp[s] = v;
            }

            // CNOT ring (0,1),(1,2),(2,3),(3,0): conditional bit-flip swaps
#pragma unroll
            for (int g = 0; g < 4; ++g) {
                const int cb = 8 >> g;
                const int tb = 8 >> ((g + 1) & 3);
#pragma unroll
                for (int s = 0; s < 16; ++s) {
                    if ((s & cb) && !(s & tb)) {
                        float tmp = amp[s];
                        amp[s] = amp[s ^ tb];
                        amp[s ^ tb] = tmp;
                    }
                }
            }

            // Trainable RY layer: Givens rotations
#pragma unroll
            for (int q = 0; q < 4; ++q) {
                const int qb = 8 >> q;
                const float cc = ct[q], sv = st[q];
#pragma unroll
                for (int s = 0; s < 16; ++s) {
                    if (!(s & qb)) {
                        float v0 = amp[s], v1 = amp[s | qb];
                        amp[s]      = cc * v0 - sv * v1;
                        amp[s | qb] = sv * v0 + cc * v1;
                    }
                }
            }

            // <Z_q>
            float z0 = 0.f, z1 = 0.f, z2 = 0.f, z3 = 0.f;
#pragma unroll
            for (int s = 0; s < 16; ++s) {
                float p = amp[s] * amp[s];
                z0 += (s & 8) ? -p : p;
                z1 += (s & 4) ? -p : p;
                z2 += (s & 2) ? -p : p;
                z3 += (s & 1) ? -p : p;
            }

            const int lsub = 2 * lpair + c;
            lds[lsub * 32 + (b ^ (lsub & 31))] = make_float4(z0, z1, z2, z3);
        }
    }

    __syncthreads();

    // Contiguous 32 KB output span per block
    float4* out4 = (float4*)out + (size_t)l0 * 32;
#pragma unroll
    for (int k = 0; k < 8; ++k) {
        const int idx = k * 256 + tid;
        const int ls = idx >> 5, bb = idx & 31;
        out4[idx] = lds[ls * 32 + (bb ^ (ls & 31))];
    }
}

extern "C" void kernel_launch(void* const* d_in, const int* in_sizes, int n_in,
                              void* d_out, int out_size, void* d_ws, size_t ws_size,
                              hipStream_t stream) {
    const float* x     = (const float*)d_in[0];
    const float* theta = (const float*)d_in[1];
    float* out         = (float*)d_out;

    const int blocks = LTOT / 64; // 1024
    quanv_kernel<<<blocks, 256, 0, stream>>>(x, theta, out);
}

// Round 7
// 80.918 us; speedup vs baseline: 1.1317x; 1.1317x over previous
//
#include <hip/hip_runtime.h>

// x:(32,1,512,512) f32, theta:(4,) f32
// out flat (reference raw .view): out_flat[l*128 + b*4 + q] -> float4 units out4[l*32+b]
// Closed form of the 4-qubit circuit (CNOT ring is GF(2)-linear; RY orthogonal):
//   <Z_q> = cos(theta_q) * prod_{r in S_q} cos(a_r) - sin(theta_q) * prod_{r in T_q} sin(a_r)
//   S0={1,2,3} S1={0,1} S2={0,1,2} S3={0,1,2,3};  T0={0,1} T1={1,2} T2={2,3} T3={0,1,3}
#define HH 512
#define WW 512
#define HO 256
#define WO 256
#define LTOT (HO * WO)

// hardware v_sin/v_cos take revolutions: sin(a) = v_sin(a/(2pi)); |a|<~6 -> in range
#define INV_2PI 0.15915494309189535f

__global__ __launch_bounds__(256) void quanv_kernel(const float* __restrict__ x,
                                                    const float* __restrict__ theta,
                                                    float* __restrict__ out) {
    __shared__ float4 lds[1024];   // 16 KB: 32 patches x 32 batches

    const int tid   = threadIdx.x;
    const int l0    = blockIdx.x * 32;   // 32 consecutive patches, same image row
    const int irow  = l0 >> 8;
    const int j0    = l0 & 255;
    const int lpair = tid & 15;          // patch-pair -> patches 2*lpair, 2*lpair+1
    const int b0    = tid >> 4;          // 0..15; handles batches b0 and b0+16

    // full-angle sin/cos of theta (uniform)
    float ct[4], st[4];
#pragma unroll
    for (int q = 0; q < 4; ++q) {
        const float r = theta[q] * INV_2PI;
        st[q] = __builtin_amdgcn_sinf(r);
        ct[q] = __builtin_amdgcn_cosf(r);
    }

    const int col  = 2 * (j0 + 2 * lpair);   // multiple of 4 -> 16B aligned
    const int off0 = (2 * irow) * WW + col;  // row 2i
    const int off1 = off0 + WW;              // row 2i+1

    // issue all 4 global loads up-front (64B/thread)
    const float* xb0 = x + (size_t)b0 * (HH * WW);
    const float* xb1 = x + (size_t)(b0 + 16) * (HH * WW);
    const float4 r0a = *(const float4*)(xb0 + off0);
    const float4 r1a = *(const float4*)(xb0 + off1);
    const float4 r0b = *(const float4*)(xb1 + off0);
    const float4 r1b = *(const float4*)(xb1 + off1);

#pragma unroll
    for (int w = 0; w < 2; ++w) {
        const int b = b0 + 16 * w;
        const float4 r0 = w ? r0b : r0a;
        const float4 r1 = w ? r1b : r1a;
#pragma unroll
        for (int c = 0; c < 2; ++c) {
            const float aa[4] = {c ? r0.z : r0.x, c ? r0.w : r0.y,
                                 c ? r1.z : r1.x, c ? r1.w : r1.y};
            float ca[4], sa[4];
#pragma unroll
            for (int k = 0; k < 4; ++k) {
                const float r = aa[k] * INV_2PI;
                sa[k] = __builtin_amdgcn_sinf(r);
                ca[k] = __builtin_amdgcn_cosf(r);
            }
            const float A1 = ca[0] * ca[1];
            const float A2 = A1 * ca[2];
            const float A3 = A2 * ca[3];
            const float A0 = (ca[1] * ca[2]) * ca[3];
            const float B0 = sa[0] * sa[1];
            const float B1 = sa[1] * sa[2];
            const float B2 = sa[2] * sa[3];
            const float B3 = B0 * sa[3];
            const float z0 = ct[0] * A0 - st[0] * B0;
            const float z1 = ct[1] * A1 - st[1] * B1;
            const float z2 = ct[2] * A2 - st[2] * B2;
            const float z3 = ct[3] * A3 - st[3] * B3;

            const int lsub = 2 * lpair + c;
            lds[lsub * 32 + (b ^ (lsub & 31))] = make_float4(z0, z1, z2, z3);
        }
    }

    __syncthreads();

    // contiguous 16 KB output span per block
    float4* out4 = (float4*)out + (size_t)l0 * 32;
#pragma unroll
    for (int k = 0; k < 4; ++k) {
        const int idx = k * 256 + tid;
        const int ls = idx >> 5, bb = idx & 31;
        out4[idx] = lds[ls * 32 + (bb ^ (ls & 31))];
    }
}

extern "C" void kernel_launch(void* const* d_in, const int* in_sizes, int n_in,
                              void* d_out, int out_size, void* d_ws, size_t ws_size,
                              hipStream_t stream) {
    const float* x     = (const float*)d_in[0];
    const float* theta = (const float*)d_in[1];
    float* out         = (float*)d_out;

    const int blocks = LTOT / 32; // 2048 -> 8 blocks/CU, 100% occupancy cap
    quanv_kernel<<<blocks, 256, 0, stream>>>(x, theta, out);
}